// Round 1
// baseline (1873.366 us; speedup 1.0000x reference)
//
#include <hip/hip_runtime.h>
#include <math.h>

#define NN 100000
#define EE 500000

// ---------------- RTE sinusoid table [240, 256] ----------------
__global__ void rte_tab_kernel(float* __restrict__ tab) {
    int p = blockIdx.x;      // 0..239
    int j = threadIdx.x;     // 0..255
    int m = j >> 1;
    // replicate fp32 overflow: 10000^(2m) -> inf for 2m >= 10 in fp32
    float pf = (float)pow(10000.0, (double)(2 * m));
    float dv = 1.0f / (pf / 128.0f / 2.0f);
    float ang = (float)p * dv;
    const float s = 0.08838834764831845f; // 1/sqrt(128)
    float v = (j & 1) ? (cosf(ang) * s) : (sinf(ang) * s);
    tab[p * 256 + j] = v;
}

// ---------------- rte_proj[p,c] = rte_tab[p,:] @ rte_w + rte_b ----------------
__global__ void rte_proj_kernel(const float* __restrict__ tab,
                                const float* __restrict__ rte_w,
                                const float* __restrict__ rte_b,
                                float* __restrict__ proj) {
    __shared__ float row[256];
    int p = blockIdx.x;           // 240
    int c = threadIdx.x;          // 128
    for (int i = threadIdx.x; i < 256; i += 128) row[i] = tab[p * 256 + i];
    __syncthreads();
    float acc = rte_b[c];
    #pragma unroll 8
    for (int q = 0; q < 256; ++q) acc += row[q] * rte_w[q * 128 + c];
    proj[p * 128 + c] = acc;
}

// ---------------- ktv[b][0:128]=proj@Wk[t], ktv[b][128:256]=proj@Wv[t] ----------------
__global__ void ktv_kernel(const float* __restrict__ proj,
                           const float* __restrict__ Wk,
                           const float* __restrict__ Wv,
                           float* __restrict__ ktv) {
    __shared__ float row[128];
    int b = blockIdx.x;           // 720 = t*240 + p
    int t = b / 240, p = b % 240;
    int c = threadIdx.x;          // 128
    row[c] = proj[p * 128 + c];
    __syncthreads();
    const float* wk = Wk + t * 16384 + c;
    const float* wv = Wv + t * 16384 + c;
    float ak = 0.f, av = 0.f;
    #pragma unroll 8
    for (int q = 0; q < 128; ++q) {
        float rv = row[q];
        ak += rv * wk[q * 128];
        av += rv * wv[q * 128];
    }
    ktv[(size_t)b * 256 + c] = ak;
    ktv[(size_t)b * 256 + 128 + c] = av;
}

// ---------------- CSR build (edges grouped by target) ----------------
__global__ void hist_kernel(const int* __restrict__ tgt, int* __restrict__ cnt) {
    int e = blockIdx.x * blockDim.x + threadIdx.x;
    if (e < EE) atomicAdd(&cnt[tgt[e]], 1);
}

__global__ void scan_kernel(const int* __restrict__ cnt, int* __restrict__ row_start) {
    __shared__ int sdata[1024];
    __shared__ int s_running;
    if (threadIdx.x == 0) s_running = 0;
    __syncthreads();
    for (int base = 0; base < NN; base += 1024) {
        int i = base + (int)threadIdx.x;
        int v = (i < NN) ? cnt[i] : 0;
        sdata[threadIdx.x] = v;
        __syncthreads();
        int acc = v;
        for (int off = 1; off < 1024; off <<= 1) {
            int t = (threadIdx.x >= (unsigned)off) ? sdata[threadIdx.x - off] : 0;
            __syncthreads();
            acc += t;
            sdata[threadIdx.x] = acc;
            __syncthreads();
        }
        int run = s_running;
        if (i < NN) row_start[i] = run + acc - v;   // exclusive
        __syncthreads();
        if (threadIdx.x == 1023) s_running = run + sdata[1023];
        __syncthreads();
    }
    if (threadIdx.x == 0) row_start[NN] = s_running;
}

// scatter + meta fused: meta[pos] = {src, (tb<<6)|(tt<<4)|(st<<2)|r, tgt, 0}
__global__ void scatter_meta_kernel(const int* __restrict__ esrc,
                                    const int* __restrict__ etgt,
                                    const int* __restrict__ etype,
                                    const int* __restrict__ etime,
                                    const int* __restrict__ node_type,
                                    const int* __restrict__ row_start,
                                    int* __restrict__ fill,
                                    int4* __restrict__ meta) {
    int e = blockIdx.x * blockDim.x + threadIdx.x;
    if (e < EE) {
        int tgt = etgt[e];
        int src = esrc[e];
        int r = etype[e];
        int tm = etime[e];
        int st = node_type[src];
        int tt = node_type[tgt];
        int tb = st * 240 + tm;
        int pos = row_start[tgt] + atomicAdd(&fill[tgt], 1);
        meta[pos] = make_int4(src, (tb << 6) | (tt << 4) | (st << 2) | r, tgt, 0);
    }
}

// ---------------- node counting sort by type (3 bins) ----------------
__global__ void node_hist_kernel(const int* __restrict__ nt, int* __restrict__ tcnt) {
    __shared__ int lc[3];
    if (threadIdx.x < 3) lc[threadIdx.x] = 0;
    __syncthreads();
    int i = blockIdx.x * blockDim.x + threadIdx.x;
    if (i < NN) atomicAdd(&lc[nt[i]], 1);
    __syncthreads();
    if (threadIdx.x < 3) atomicAdd(&tcnt[threadIdx.x], lc[threadIdx.x]);
}

__global__ void node_scatter_kernel(const int* __restrict__ nt,
                                    const int* __restrict__ tcnt,
                                    int* __restrict__ fill3,
                                    int* __restrict__ order) {
    __shared__ int lc[3], lbase[3], lfill[3];
    if (threadIdx.x < 3) { lc[threadIdx.x] = 0; lfill[threadIdx.x] = 0; }
    __syncthreads();
    int i = blockIdx.x * blockDim.x + threadIdx.x;
    int t = -1;
    if (i < NN) { t = nt[i]; atomicAdd(&lc[t], 1); }
    __syncthreads();
    if (threadIdx.x < 3) lbase[threadIdx.x] = atomicAdd(&fill3[threadIdx.x], lc[threadIdx.x]);
    __syncthreads();
    if (i < NN) {
        int rank = atomicAdd(&lfill[t], 1);
        int tb = (t == 0) ? 0 : ((t == 1) ? tcnt[0] : tcnt[0] + tcnt[1]);
        order[tb + lbase[t] + rank] = i;
    }
}

// ---------------- typed linear over type-sorted nodes ----------------
template <int MODE>
__global__ __launch_bounds__(256) void typed_lin_kernel(
    const float* __restrict__ in, const int* __restrict__ nt,
    const int* __restrict__ order,
    const float* __restrict__ W, const float* __restrict__ b,
    const float* __restrict__ skip, float* __restrict__ out) {
    __shared__ float xs[32][128];
    __shared__ int rows[32];
    __shared__ int sty[32];
    int nb = blockIdx.x * 32;
    if (threadIdx.x < 32) {
        int r = order[nb + threadIdx.x];
        rows[threadIdx.x] = r;
        sty[threadIdx.x] = nt[r];
    }
    __syncthreads();
    for (int i = threadIdx.x; i < 1024; i += 256) {
        int nl = i >> 5, e4 = i & 31;
        *(float4*)&xs[nl][e4 * 4] = *(const float4*)(in + (size_t)rows[nl] * 128 + e4 * 4);
    }
    __syncthreads();
    int col = threadIdx.x & 127;
    int ng  = (threadIdx.x >> 7) * 16;
    int t0 = sty[ng];
    bool uni = true;
    #pragma unroll
    for (int ii = 1; ii < 16; ++ii) uni &= (sty[ng + ii] == t0);
    if (uni) {
        const float* w = W + t0 * 16384 + col;
        float bv = b[t0 * 128 + col];
        float alpha = (MODE == 1) ? (1.f / (1.f + __expf(-skip[t0]))) : 0.f;
        float acc[16];
        #pragma unroll
        for (int ii = 0; ii < 16; ++ii) acc[ii] = bv;
        for (int k0 = 0; k0 < 128; k0 += 4) {
            float w0 = w[(k0 + 0) * 128];
            float w1 = w[(k0 + 1) * 128];
            float w2 = w[(k0 + 2) * 128];
            float w3 = w[(k0 + 3) * 128];
            #pragma unroll
            for (int ii = 0; ii < 16; ++ii) {
                float4 xv = *(const float4*)&xs[ng + ii][k0];
                acc[ii] += xv.x * w0 + xv.y * w1 + xv.z * w2 + xv.w * w3;
            }
        }
        #pragma unroll
        for (int ii = 0; ii < 16; ++ii) {
            size_t gi = (size_t)rows[ng + ii] * 128 + col;
            if (MODE == 0) out[gi] = tanhf(acc[ii]);
            else           out[gi] = alpha * acc[ii] + (1.f - alpha) * out[gi];
        }
    } else {
        for (int ii = 0; ii < 16; ++ii) {
            int nl = ng + ii;
            int t = sty[nl];
            const float* w = W + t * 16384 + col;
            float acc = b[t * 128 + col];
            #pragma unroll 8
            for (int k = 0; k < 128; ++k) acc += xs[nl][k] * w[k * 128];
            size_t gi = (size_t)rows[nl] * 128 + col;
            if (MODE == 0) out[gi] = tanhf(acc);
            else {
                float alpha = 1.f / (1.f + __expf(-skip[t]));
                out[gi] = alpha * acc + (1.f - alpha) * out[gi];
            }
        }
    }
}

// ---------------- fused Q/K/V typed projections; K/V interleaved per row ----------------
__global__ __launch_bounds__(256) void qkv_kernel(
    const float* __restrict__ x, const int* __restrict__ nt,
    const int* __restrict__ order,
    const float* __restrict__ Wq, const float* __restrict__ bq,
    const float* __restrict__ Wk, const float* __restrict__ bk,
    const float* __restrict__ Wv, const float* __restrict__ bv,
    float* __restrict__ Qn, float* __restrict__ KV) {
    __shared__ float xs[32][128];
    __shared__ int rows[32];
    __shared__ int sty[32];
    int nb = blockIdx.x * 32;
    if (threadIdx.x < 32) {
        int r = order[nb + threadIdx.x];
        rows[threadIdx.x] = r;
        sty[threadIdx.x] = nt[r];
    }
    __syncthreads();
    for (int i = threadIdx.x; i < 1024; i += 256) {
        int nl = i >> 5, e4 = i & 31;
        *(float4*)&xs[nl][e4 * 4] = *(const float4*)(x + (size_t)rows[nl] * 128 + e4 * 4);
    }
    __syncthreads();
    int col = threadIdx.x & 127;
    int ng  = (threadIdx.x >> 7) * 16;
    int t0 = sty[ng];
    bool uni = true;
    #pragma unroll
    for (int ii = 1; ii < 16; ++ii) uni &= (sty[ng + ii] == t0);
    if (uni) {
        const float* wq = Wq + t0 * 16384 + col;
        const float* wk = Wk + t0 * 16384 + col;
        const float* wv = Wv + t0 * 16384 + col;
        float bqv = bq[t0 * 128 + col];
        float bkv = bk[t0 * 128 + col];
        float bvv = bv[t0 * 128 + col];
        float aq[16], ak[16], av[16];
        #pragma unroll
        for (int ii = 0; ii < 16; ++ii) { aq[ii] = bqv; ak[ii] = bkv; av[ii] = bvv; }
        for (int k0 = 0; k0 < 128; k0 += 4) {
            float q0 = wq[(k0 + 0) * 128], q1 = wq[(k0 + 1) * 128];
            float q2 = wq[(k0 + 2) * 128], q3 = wq[(k0 + 3) * 128];
            float k0w = wk[(k0 + 0) * 128], k1w = wk[(k0 + 1) * 128];
            float k2w = wk[(k0 + 2) * 128], k3w = wk[(k0 + 3) * 128];
            float v0 = wv[(k0 + 0) * 128], v1 = wv[(k0 + 1) * 128];
            float v2 = wv[(k0 + 2) * 128], v3 = wv[(k0 + 3) * 128];
            #pragma unroll
            for (int ii = 0; ii < 16; ++ii) {
                float4 xv = *(const float4*)&xs[ng + ii][k0];
                aq[ii] += xv.x * q0 + xv.y * q1 + xv.z * q2 + xv.w * q3;
                ak[ii] += xv.x * k0w + xv.y * k1w + xv.z * k2w + xv.w * k3w;
                av[ii] += xv.x * v0 + xv.y * v1 + xv.z * v2 + xv.w * v3;
            }
        }
        #pragma unroll
        for (int ii = 0; ii < 16; ++ii) {
            size_t row = (size_t)rows[ng + ii];
            Qn[row * 128 + col] = aq[ii];
            KV[row * 256 + col] = ak[ii];
            KV[row * 256 + 128 + col] = av[ii];
        }
    } else {
        for (int ii = 0; ii < 16; ++ii) {
            int nl = ng + ii;
            int t = sty[nl];
            const float* wq = Wq + t * 16384 + col;
            const float* wk = Wk + t * 16384 + col;
            const float* wv = Wv + t * 16384 + col;
            float aq = bq[t * 128 + col];
            float ak = bk[t * 128 + col];
            float av = bv[t * 128 + col];
            #pragma unroll 4
            for (int k = 0; k < 128; ++k) {
                float xv = xs[nl][k];
                aq += xv * wq[k * 128];
                ak += xv * wk[k * 128];
                av += xv * wv[k * 128];
            }
            size_t row = (size_t)rows[nl];
            Qn[row * 128 + col] = aq;
            KV[row * 256 + col] = ak;
            KV[row * 256 + 128 + col] = av;
        }
    }
}

// ---------------- fused score + softmax + aggregation (wave per node) ----------------
// Replaces score2_kernel + aggr_kernel: one latency pass over the edge set.
// Per wave: prefetch meta chunk -> compute qA (overlaps meta latency) ->
//   [score 8 edges x 8 heads -> p into wave-private LDS] -> barrier ->
//   [serial v-aggregation reading p from LDS] -> epilogue rel_msg + 1/sum(p) + gelu.
// LDS per wave: qAs(512) + union{qrow(128) | p_lds(512) | accb(544)} = 1056 floats.
__global__ __launch_bounds__(256) void edge_kernel(
    const float* __restrict__ Qn, const float* __restrict__ KV,
    const float* __restrict__ ktv, const int4* __restrict__ meta,
    const int* __restrict__ node_type,
    const float* __restrict__ rel_pri, const float* __restrict__ rel_att,
    const float* __restrict__ rel_msg, const int* __restrict__ row_start,
    float* __restrict__ h_out) {
    __shared__ float smem[4][1056];
    __shared__ int chs[4];
    int w = threadIdx.x >> 6;
    int lane = threadIdx.x & 63;
    int n = blockIdx.x * 4 + w;       // grid = NN/4 exactly
    float* qAs_w   = smem[w];         // [r*128 + h*16 + i], live after prologue
    float* scratch = smem[w] + 512;   // qrow (prologue) / p_lds (chunks) / accb (epilogue)

    // ---- early independent loads: CSR bounds + first meta chunk in flight
    // while the qA precompute runs on the VALU ----
    int e_beg = row_start[n], e_end = row_start[n + 1];
    int tt = node_type[n];
    int4 mm0 = make_int4(0, 0, 0, 0);
    if (e_beg + lane < e_end) mm0 = meta[e_beg + lane];

    // stage q row into scratch (qrow role)
    float2 q2 = *(const float2*)(Qn + (size_t)n * 128 + lane * 2);
    *(float2*)&scratch[lane * 2] = q2;
    if (lane == 0) chs[w] = (e_end - e_beg + 63) >> 6;
    __syncthreads();
    int nch = max(max(chs[0], chs[1]), max(chs[2], chs[3]));  // block-uniform chunk count

    // qA[r][h][i] = sum_k q[h*16+k] * rel_att[r][h][k][i]
    #pragma unroll
    for (int u = 0; u < 8; ++u) {
        int f = u * 64 + lane;        // 0..511
        int rem = f & 127;
        int hh = rem >> 4;
        const float4* A4 = (const float4*)(rel_att + (size_t)f * 16);
        float4 a0 = A4[0], a1 = A4[1], a2 = A4[2], a3 = A4[3];
        const float* qq = &scratch[hh * 16];
        float val = a0.x * qq[0] + a0.y * qq[1] + a0.z * qq[2] + a0.w * qq[3]
                  + a1.x * qq[4] + a1.y * qq[5] + a1.z * qq[6] + a1.w * qq[7]
                  + a2.x * qq[8] + a2.y * qq[9] + a2.z * qq[10] + a2.w * qq[11]
                  + a3.x * qq[12] + a3.y * qq[13] + a3.z * qq[14] + a3.w * qq[15];
        qAs_w[f] = val;
    }
    __syncthreads();   // qAs ready; qrow dead -> scratch becomes p_lds

    int j = lane >> 3, h = lane & 7;          // score mapping: lane = j*8 + h
    int h2 = lane >> 3, d0 = lane * 2;        // aggr mapping: lane owns head h2, dims d0,d0+1
    int cp = d0 & 15;
    float ls = 0.f;
    float2 a0v = {0.f, 0.f}, a1v = {0.f, 0.f}, a2v = {0.f, 0.f}, a3v = {0.f, 0.f};
    int rmask = 0;

    for (int c = 0; c < nch; ++c) {
        int cb = e_beg + (c << 6);
        bool active = cb < e_end;
        int4 mm = mm0;
        if (c > 0) {
            mm = make_int4(0, 0, 0, 0);
            if (active && (cb + lane) < e_end) mm = meta[cb + lane];
        }
        // ---- score phase: 8 edges x 8 heads per sub-iter; p -> p_lds ----
        if (active) {
            int nss = (min(64, e_end - cb) + 7) >> 3;
            for (int ss = 0; ss < nss; ++ss) {
                int icb = ss << 3;
                int ei = cb + icb + j;
                bool valid = ei < e_end;
                int mxs = __shfl(mm.x, icb + j, 64);
                int mys = __shfl(mm.y, icb + j, 64);
                int r = mys & 3, st = (mys >> 2) & 3, tb = mys >> 6;
                const float4* kp = (const float4*)(KV + (size_t)mxs * 256 + h * 16);
                const float4* tp = (const float4*)(ktv + (size_t)tb * 256 + h * 16);
                float4 k0 = kp[0], k1 = kp[1], k2 = kp[2], k3 = kp[3];
                float4 t0 = tp[0], t1 = tp[1], t2 = tp[2], t3 = tp[3];
                const float* qa = qAs_w + r * 128 + h * 16;
                float s = (k0.x + t0.x) * qa[0]  + (k0.y + t0.y) * qa[1]
                        + (k0.z + t0.z) * qa[2]  + (k0.w + t0.w) * qa[3]
                        + (k1.x + t1.x) * qa[4]  + (k1.y + t1.y) * qa[5]
                        + (k1.z + t1.z) * qa[6]  + (k1.w + t1.w) * qa[7]
                        + (k2.x + t2.x) * qa[8]  + (k2.y + t2.y) * qa[9]
                        + (k2.z + t2.z) * qa[10] + (k2.w + t2.w) * qa[11]
                        + (k3.x + t3.x) * qa[12] + (k3.y + t3.y) * qa[13]
                        + (k3.z + t3.z) * qa[14] + (k3.w + t3.w) * qa[15];
                float pri = rel_pri[((tt * 4 + r) * 3 + st) * 8 + h];
                float p = valid ? __expf(s * pri * 0.25f) : 0.f;
                scratch[icb * 8 + lane] = p;   // p_lds[(icb+j)*8 + h], conflict-free
                ls += p;
            }
        }
        __syncthreads();
        // ---- aggregation phase: serial over chunk edges, v gathered coalesced ----
        if (active) {
            int cdeg = min(64, e_end - cb);
            int mx = mm.x, my = mm.y;
            #pragma unroll 4
            for (int i = 0; i < cdeg; ++i) {
                int src  = __shfl(mx, i, 64);
                int code = __shfl(my, i, 64);
                int r = code & 3;
                float pv = scratch[i * 8 + h2];   // broadcast within 8-lane groups
                float2 v1 = *(const float2*)(KV + (size_t)src * 256 + 128 + d0);
                float2 v2 = *(const float2*)(ktv + (size_t)(code >> 6) * 256 + 128 + d0);
                float vx = pv * (v1.x + v2.x);
                float vy = pv * (v1.y + v2.y);
                rmask |= (1 << r);
                switch (r) {
                    case 0: a0v.x += vx; a0v.y += vy; break;
                    case 1: a1v.x += vx; a1v.y += vy; break;
                    case 2: a2v.x += vx; a2v.y += vy; break;
                    default: a3v.x += vx; a3v.y += vy; break;
                }
            }
        }
        __syncthreads();   // p_lds consumed; safe to overwrite next chunk / epilogue
    }

    // ---- softmax denominator: reduce p-sums over the 8 edge-slot lanes ----
    ls += __shfl_xor(ls, 8, 64);
    ls += __shfl_xor(ls, 16, 64);
    ls += __shfl_xor(ls, 32, 64);

    // ---- epilogue: acc -> LDS (accb role), rel_msg transform, 1/ls, gelu ----
    int li = h2 * 17 + cp;   // padded stride 17 vs bank conflicts
    scratch[0 * 136 + li] = a0v.x; scratch[0 * 136 + li + 1] = a0v.y;
    scratch[1 * 136 + li] = a1v.x; scratch[1 * 136 + li + 1] = a1v.y;
    scratch[2 * 136 + li] = a2v.x; scratch[2 * 136 + li + 1] = a2v.y;
    scratch[3 * 136 + li] = a3v.x; scratch[3 * 136 + li + 1] = a3v.y;
    __syncthreads();
    float o0 = 0.f, o1 = 0.f;
    const float* M = rel_msg + h2 * 256 + cp;
    #pragma unroll
    for (int r = 0; r < 4; ++r) {
        if (rmask & (1 << r)) {
            #pragma unroll
            for (int i = 0; i < 16; ++i) {
                float av = scratch[r * 136 + h2 * 17 + i];
                float2 mm2 = *(const float2*)(M + r * 2048 + i * 16);
                o0 += av * mm2.x;
                o1 += av * mm2.y;
            }
        }
    }
    float lst = __shfl(ls, h2, 64);            // lane h2 holds total for head h2
    float iv = (lst > 0.f) ? (1.f / lst) : 0.f;
    o0 *= iv; o1 *= iv;
    // exact gelu
    o0 = 0.5f * o0 * (1.f + erff(o0 * 0.7071067811865475f));
    o1 = 0.5f * o1 * (1.f + erff(o1 * 0.7071067811865475f));
    *(float2*)(h_out + (size_t)n * 128 + d0) = make_float2(o0, o1);
}

// ---------------- launcher ----------------
extern "C" void kernel_launch(void* const* d_in, const int* in_sizes, int n_in,
                              void* d_out, int out_size, void* d_ws, size_t ws_size,
                              hipStream_t stream) {
    const float* node_feature = (const float*)d_in[0];
    const int*   node_type    = (const int*)d_in[1];
    const int*   edge_index   = (const int*)d_in[2];   // [2,E]: src then tgt
    const int*   edge_type    = (const int*)d_in[3];
    const int*   edge_time    = (const int*)d_in[4];
    const float* adapt_w      = (const float*)d_in[5];
    const float* adapt_b      = (const float*)d_in[6];
    const float* Wk           = (const float*)d_in[7];
    const float* bk           = (const float*)d_in[8];
    const float* Wq           = (const float*)d_in[9];
    const float* bq           = (const float*)d_in[10];
    const float* Wv           = (const float*)d_in[11];
    const float* bv           = (const float*)d_in[12];
    const float* Wa           = (const float*)d_in[13];
    const float* ba           = (const float*)d_in[14];
    const float* rel_pri      = (const float*)d_in[15];
    const float* rel_att      = (const float*)d_in[16];
    const float* rel_msg      = (const float*)d_in[17];
    const float* skip         = (const float*)d_in[18];
    const float* rte_w        = (const float*)d_in[19];
    const float* rte_b        = (const float*)d_in[20];
    float* out = (float*)d_out;

    const size_t ND = (size_t)NN * 128;
    float* Qn     = (float*)d_ws;            // N*128 (reused as h buffer)
    float* KV     = Qn + ND;                 // N*256 (k|v per row)
    float* rtab   = KV + 2 * ND;             // 240*256
    float* rproj  = rtab + 240 * 256;        // 240*128
    float* ktv    = rproj + 240 * 128;       // 720*256 (k|v per row)
    int*   cnt    = (int*)(ktv + 720 * 256);
    int*   fill   = cnt + NN;
    int*   row_st = fill + NN;               // NN+1 (+pad)
    int*   order  = row_st + NN + 4;         // NN
    int*   tcnt   = order + NN;              // 3 (+pad)
    int*   fill3  = tcnt + 4;                // 3 (+pad)
    int4*  meta   = (int4*)(fill3 + 4);      // EE int4
    // total ~165 MB (p/inv buffers removed by score+aggr fusion)

    const int* esrc = edge_index;
    const int* etgt = edge_index + EE;

    hipMemsetAsync(cnt, 0, 2 * NN * sizeof(int), stream);
    hipMemsetAsync(tcnt, 0, 8 * sizeof(int), stream);
    rte_tab_kernel<<<240, 256, 0, stream>>>(rtab);
    hist_kernel<<<(EE + 255) / 256, 256, 0, stream>>>(etgt, cnt);
    scan_kernel<<<1, 1024, 0, stream>>>(cnt, row_st);
    scatter_meta_kernel<<<(EE + 255) / 256, 256, 0, stream>>>(esrc, etgt, edge_type,
                                                              edge_time, node_type,
                                                              row_st, fill, meta);
    node_hist_kernel<<<(NN + 255) / 256, 256, 0, stream>>>(node_type, tcnt);
    node_scatter_kernel<<<(NN + 255) / 256, 256, 0, stream>>>(node_type, tcnt, fill3, order);

    // input adaptation: x = tanh(typed_linear(node_feature))
    typed_lin_kernel<0><<<NN / 32, 256, 0, stream>>>(node_feature, node_type, order,
                                                     adapt_w, adapt_b, nullptr, out);

    for (int l = 0; l < 2; ++l) {
        const float* Wk_l = Wk + l * 49152;  const float* bk_l = bk + l * 384;
        const float* Wq_l = Wq + l * 49152;  const float* bq_l = bq + l * 384;
        const float* Wv_l = Wv + l * 49152;  const float* bv_l = bv + l * 384;
        const float* Wa_l = Wa + l * 49152;  const float* ba_l = ba + l * 384;
        const float* pri_l = rel_pri + l * 288;
        const float* att_l = rel_att + l * 8192;
        const float* msg_l = rel_msg + l * 8192;
        const float* skip_l = skip + l * 3;
        const float* rte_w_l = rte_w + l * 32768;
        const float* rte_b_l = rte_b + l * 128;

        rte_proj_kernel<<<240, 128, 0, stream>>>(rtab, rte_w_l, rte_b_l, rproj);
        ktv_kernel<<<720, 128, 0, stream>>>(rproj, Wk_l, Wv_l, ktv);
        qkv_kernel<<<NN / 32, 256, 0, stream>>>(out, node_type, order, Wq_l, bq_l,
                                                Wk_l, bk_l, Wv_l, bv_l, Qn, KV);
        edge_kernel<<<NN / 4, 256, 0, stream>>>(Qn, KV, ktv, meta, node_type,
                                                pri_l, att_l, msg_l, row_st,
                                                Qn /* h overwrites own Qn rows: safe */);
        typed_lin_kernel<1><<<NN / 32, 256, 0, stream>>>(Qn, node_type, order, Wa_l, ba_l,
                                                         skip_l, out);
    }
}

// Round 3
// 1679.540 us; speedup vs baseline: 1.1154x; 1.1154x over previous
//
#include <hip/hip_runtime.h>
#include <math.h>

#define NN 100000
#define EE 500000

// ---------------- RTE sinusoid table [240, 256] ----------------
__global__ void rte_tab_kernel(float* __restrict__ tab) {
    int p = blockIdx.x;      // 0..239
    int j = threadIdx.x;     // 0..255
    int m = j >> 1;
    // replicate fp32 overflow: 10000^(2m) -> inf for 2m >= 10 in fp32
    float pf = (float)pow(10000.0, (double)(2 * m));
    float dv = 1.0f / (pf / 128.0f / 2.0f);
    float ang = (float)p * dv;
    const float s = 0.08838834764831845f; // 1/sqrt(128)
    float v = (j & 1) ? (cosf(ang) * s) : (sinf(ang) * s);
    tab[p * 256 + j] = v;
}

// ---------------- rte_proj[p,c] = rte_tab[p,:] @ rte_w + rte_b ----------------
__global__ void rte_proj_kernel(const float* __restrict__ tab,
                                const float* __restrict__ rte_w,
                                const float* __restrict__ rte_b,
                                float* __restrict__ proj) {
    __shared__ float row[256];
    int p = blockIdx.x;           // 240
    int c = threadIdx.x;          // 128
    for (int i = threadIdx.x; i < 256; i += 128) row[i] = tab[p * 256 + i];
    __syncthreads();
    float acc = rte_b[c];
    #pragma unroll 8
    for (int q = 0; q < 256; ++q) acc += row[q] * rte_w[q * 128 + c];
    proj[p * 128 + c] = acc;
}

// ---------------- ktv[b][0:128]=proj@Wk[t], ktv[b][128:256]=proj@Wv[t] ----------------
__global__ void ktv_kernel(const float* __restrict__ proj,
                           const float* __restrict__ Wk,
                           const float* __restrict__ Wv,
                           float* __restrict__ ktv) {
    __shared__ float row[128];
    int b = blockIdx.x;           // 720 = t*240 + p
    int t = b / 240, p = b % 240;
    int c = threadIdx.x;          // 128
    row[c] = proj[p * 128 + c];
    __syncthreads();
    const float* wk = Wk + t * 16384 + c;
    const float* wv = Wv + t * 16384 + c;
    float ak = 0.f, av = 0.f;
    #pragma unroll 8
    for (int q = 0; q < 128; ++q) {
        float rv = row[q];
        ak += rv * wk[q * 128];
        av += rv * wv[q * 128];
    }
    ktv[(size_t)b * 256 + c] = ak;
    ktv[(size_t)b * 256 + 128 + c] = av;
}

// ---------------- CSR build (edges grouped by target) ----------------
__global__ void hist_kernel(const int* __restrict__ tgt, int* __restrict__ cnt) {
    int e = blockIdx.x * blockDim.x + threadIdx.x;
    if (e < EE) atomicAdd(&cnt[tgt[e]], 1);
}

__global__ void scan_kernel(const int* __restrict__ cnt, int* __restrict__ row_start) {
    __shared__ int sdata[1024];
    __shared__ int s_running;
    if (threadIdx.x == 0) s_running = 0;
    __syncthreads();
    for (int base = 0; base < NN; base += 1024) {
        int i = base + (int)threadIdx.x;
        int v = (i < NN) ? cnt[i] : 0;
        sdata[threadIdx.x] = v;
        __syncthreads();
        int acc = v;
        for (int off = 1; off < 1024; off <<= 1) {
            int t = (threadIdx.x >= (unsigned)off) ? sdata[threadIdx.x - off] : 0;
            __syncthreads();
            acc += t;
            sdata[threadIdx.x] = acc;
            __syncthreads();
        }
        int run = s_running;
        if (i < NN) row_start[i] = run + acc - v;   // exclusive
        __syncthreads();
        if (threadIdx.x == 1023) s_running = run + sdata[1023];
        __syncthreads();
    }
    if (threadIdx.x == 0) row_start[NN] = s_running;
}

// scatter + meta fused: meta[pos] = {src, (tb<<6)|(tt<<4)|(st<<2)|r, tgt, 0}
__global__ void scatter_meta_kernel(const int* __restrict__ esrc,
                                    const int* __restrict__ etgt,
                                    const int* __restrict__ etype,
                                    const int* __restrict__ etime,
                                    const int* __restrict__ node_type,
                                    const int* __restrict__ row_start,
                                    int* __restrict__ fill,
                                    int4* __restrict__ meta) {
    int e = blockIdx.x * blockDim.x + threadIdx.x;
    if (e < EE) {
        int tgt = etgt[e];
        int src = esrc[e];
        int r = etype[e];
        int tm = etime[e];
        int st = node_type[src];
        int tt = node_type[tgt];
        int tb = st * 240 + tm;
        int pos = row_start[tgt] + atomicAdd(&fill[tgt], 1);
        meta[pos] = make_int4(src, (tb << 6) | (tt << 4) | (st << 2) | r, tgt, 0);
    }
}

// ---------------- node counting sort by type (3 bins) ----------------
__global__ void node_hist_kernel(const int* __restrict__ nt, int* __restrict__ tcnt) {
    __shared__ int lc[3];
    if (threadIdx.x < 3) lc[threadIdx.x] = 0;
    __syncthreads();
    int i = blockIdx.x * blockDim.x + threadIdx.x;
    if (i < NN) atomicAdd(&lc[nt[i]], 1);
    __syncthreads();
    if (threadIdx.x < 3) atomicAdd(&tcnt[threadIdx.x], lc[threadIdx.x]);
}

__global__ void node_scatter_kernel(const int* __restrict__ nt,
                                    const int* __restrict__ tcnt,
                                    int* __restrict__ fill3,
                                    int* __restrict__ order) {
    __shared__ int lc[3], lbase[3], lfill[3];
    if (threadIdx.x < 3) { lc[threadIdx.x] = 0; lfill[threadIdx.x] = 0; }
    __syncthreads();
    int i = blockIdx.x * blockDim.x + threadIdx.x;
    int t = -1;
    if (i < NN) { t = nt[i]; atomicAdd(&lc[t], 1); }
    __syncthreads();
    if (threadIdx.x < 3) lbase[threadIdx.x] = atomicAdd(&fill3[threadIdx.x], lc[threadIdx.x]);
    __syncthreads();
    if (i < NN) {
        int rank = atomicAdd(&lfill[t], 1);
        int tb = (t == 0) ? 0 : ((t == 1) ? tcnt[0] : tcnt[0] + tcnt[1]);
        order[tb + lbase[t] + rank] = i;
    }
}

// ---------------- typed linear over type-sorted nodes ----------------
template <int MODE>
__global__ __launch_bounds__(256) void typed_lin_kernel(
    const float* __restrict__ in, const int* __restrict__ nt,
    const int* __restrict__ order,
    const float* __restrict__ W, const float* __restrict__ b,
    const float* __restrict__ skip, float* __restrict__ out) {
    __shared__ float xs[32][128];
    __shared__ int rows[32];
    __shared__ int sty[32];
    int nb = blockIdx.x * 32;
    if (threadIdx.x < 32) {
        int r = order[nb + threadIdx.x];
        rows[threadIdx.x] = r;
        sty[threadIdx.x] = nt[r];
    }
    __syncthreads();
    for (int i = threadIdx.x; i < 1024; i += 256) {
        int nl = i >> 5, e4 = i & 31;
        *(float4*)&xs[nl][e4 * 4] = *(const float4*)(in + (size_t)rows[nl] * 128 + e4 * 4);
    }
    __syncthreads();
    int col = threadIdx.x & 127;
    int ng  = (threadIdx.x >> 7) * 16;
    int t0 = sty[ng];
    bool uni = true;
    #pragma unroll
    for (int ii = 1; ii < 16; ++ii) uni &= (sty[ng + ii] == t0);
    if (uni) {
        const float* w = W + t0 * 16384 + col;
        float bv = b[t0 * 128 + col];
        float alpha = (MODE == 1) ? (1.f / (1.f + __expf(-skip[t0]))) : 0.f;
        float acc[16];
        #pragma unroll
        for (int ii = 0; ii < 16; ++ii) acc[ii] = bv;
        for (int k0 = 0; k0 < 128; k0 += 4) {
            float w0 = w[(k0 + 0) * 128];
            float w1 = w[(k0 + 1) * 128];
            float w2 = w[(k0 + 2) * 128];
            float w3 = w[(k0 + 3) * 128];
            #pragma unroll
            for (int ii = 0; ii < 16; ++ii) {
                float4 xv = *(const float4*)&xs[ng + ii][k0];
                acc[ii] += xv.x * w0 + xv.y * w1 + xv.z * w2 + xv.w * w3;
            }
        }
        #pragma unroll
        for (int ii = 0; ii < 16; ++ii) {
            size_t gi = (size_t)rows[ng + ii] * 128 + col;
            if (MODE == 0) out[gi] = tanhf(acc[ii]);
            else           out[gi] = alpha * acc[ii] + (1.f - alpha) * out[gi];
        }
    } else {
        for (int ii = 0; ii < 16; ++ii) {
            int nl = ng + ii;
            int t = sty[nl];
            const float* w = W + t * 16384 + col;
            float acc = b[t * 128 + col];
            #pragma unroll 8
            for (int k = 0; k < 128; ++k) acc += xs[nl][k] * w[k * 128];
            size_t gi = (size_t)rows[nl] * 128 + col;
            if (MODE == 0) out[gi] = tanhf(acc);
            else {
                float alpha = 1.f / (1.f + __expf(-skip[t]));
                out[gi] = alpha * acc + (1.f - alpha) * out[gi];
            }
        }
    }
}

// ---------------- fused Q/K/V typed projections; K/V interleaved per row ----------------
__global__ __launch_bounds__(256) void qkv_kernel(
    const float* __restrict__ x, const int* __restrict__ nt,
    const int* __restrict__ order,
    const float* __restrict__ Wq, const float* __restrict__ bq,
    const float* __restrict__ Wk, const float* __restrict__ bk,
    const float* __restrict__ Wv, const float* __restrict__ bv,
    float* __restrict__ Qn, float* __restrict__ KV) {
    __shared__ float xs[32][128];
    __shared__ int rows[32];
    __shared__ int sty[32];
    int nb = blockIdx.x * 32;
    if (threadIdx.x < 32) {
        int r = order[nb + threadIdx.x];
        rows[threadIdx.x] = r;
        sty[threadIdx.x] = nt[r];
    }
    __syncthreads();
    for (int i = threadIdx.x; i < 1024; i += 256) {
        int nl = i >> 5, e4 = i & 31;
        *(float4*)&xs[nl][e4 * 4] = *(const float4*)(x + (size_t)rows[nl] * 128 + e4 * 4);
    }
    __syncthreads();
    int col = threadIdx.x & 127;
    int ng  = (threadIdx.x >> 7) * 16;
    int t0 = sty[ng];
    bool uni = true;
    #pragma unroll
    for (int ii = 1; ii < 16; ++ii) uni &= (sty[ng + ii] == t0);
    if (uni) {
        const float* wq = Wq + t0 * 16384 + col;
        const float* wk = Wk + t0 * 16384 + col;
        const float* wv = Wv + t0 * 16384 + col;
        float bqv = bq[t0 * 128 + col];
        float bkv = bk[t0 * 128 + col];
        float bvv = bv[t0 * 128 + col];
        float aq[16], ak[16], av[16];
        #pragma unroll
        for (int ii = 0; ii < 16; ++ii) { aq[ii] = bqv; ak[ii] = bkv; av[ii] = bvv; }
        for (int k0 = 0; k0 < 128; k0 += 4) {
            float q0 = wq[(k0 + 0) * 128], q1 = wq[(k0 + 1) * 128];
            float q2 = wq[(k0 + 2) * 128], q3 = wq[(k0 + 3) * 128];
            float k0w = wk[(k0 + 0) * 128], k1w = wk[(k0 + 1) * 128];
            float k2w = wk[(k0 + 2) * 128], k3w = wk[(k0 + 3) * 128];
            float v0 = wv[(k0 + 0) * 128], v1 = wv[(k0 + 1) * 128];
            float v2 = wv[(k0 + 2) * 128], v3 = wv[(k0 + 3) * 128];
            #pragma unroll
            for (int ii = 0; ii < 16; ++ii) {
                float4 xv = *(const float4*)&xs[ng + ii][k0];
                aq[ii] += xv.x * q0 + xv.y * q1 + xv.z * q2 + xv.w * q3;
                ak[ii] += xv.x * k0w + xv.y * k1w + xv.z * k2w + xv.w * k3w;
                av[ii] += xv.x * v0 + xv.y * v1 + xv.z * v2 + xv.w * v3;
            }
        }
        #pragma unroll
        for (int ii = 0; ii < 16; ++ii) {
            size_t row = (size_t)rows[ng + ii];
            Qn[row * 128 + col] = aq[ii];
            KV[row * 256 + col] = ak[ii];
            KV[row * 256 + 128 + col] = av[ii];
        }
    } else {
        for (int ii = 0; ii < 16; ++ii) {
            int nl = ng + ii;
            int t = sty[nl];
            const float* wq = Wq + t * 16384 + col;
            const float* wk = Wk + t * 16384 + col;
            const float* wv = Wv + t * 16384 + col;
            float aq = bq[t * 128 + col];
            float ak = bk[t * 128 + col];
            float av = bv[t * 128 + col];
            #pragma unroll 4
            for (int k = 0; k < 128; ++k) {
                float xv = xs[nl][k];
                aq += xv * wq[k * 128];
                ak += xv * wk[k * 128];
                av += xv * wv[k * 128];
            }
            size_t row = (size_t)rows[nl];
            Qn[row * 128 + col] = aq;
            KV[row * 256 + col] = ak;
            KV[row * 256 + 128 + col] = av;
        }
    }
}

// ---------------- fused score + softmax + aggregation, LDS-staged tables ----------------
// Block = 4 waves, 32 nodes (8 sequential nodes per wave).
// rel_att + rel_msg staged in LDS ONCE per block: kills the per-wave 64 KB
// L2 broadcast-table read that dominated the previous kernel.
// At layout: At[l*512 + (r*8+h)*16 + k] = rel_att[r][h][k][l]
//   -> prologue contracts over A's LAST index l (qA[r][h][k] = sum_l q[h,l]*A[r,h,k,l]),
//      reads stride-512 over l (bank-invariant), lane-consecutive f (conflict-free).
//   (Round-2 bug: staged [k*512+f(l)] which made the prologue contract over k -> q^T A.)
// No barriers after staging: all main-loop LDS is wave-private (same-wave DS
// ops complete in order, so score->aggr p handoff needs no __syncthreads).
__global__ __launch_bounds__(256) void edge_kernel(
    const float* __restrict__ Qn, const float* __restrict__ KV,
    const float* __restrict__ ktv, const int4* __restrict__ meta,
    const int* __restrict__ node_type,
    const float* __restrict__ rel_pri, const float* __restrict__ rel_att,
    const float* __restrict__ rel_msg, const int* __restrict__ row_start,
    float* __restrict__ h_out) {
    __shared__ float At[16 * 512];     // At[l*512 + f], f=(r*8+h)*16+k  (32768 B)
    __shared__ float Ml[4 * 2080];     // Ml[r*2080 + h*260 + i*16 + c]  (33280 B)
    __shared__ float scr[4][768];      // per wave: [0:512)=qA, [512:768)=p (32e x 8h)

    int tid = threadIdx.x;
    // ---- stage tables (once per block) ----
    for (int g0 = tid * 4; g0 < 8192; g0 += 1024) {
        float4 a = *(const float4*)(rel_att + g0);
        int la = g0 & 15, ka = (g0 >> 4) & 15, rh = g0 >> 8;
        At[(la + 0) * 512 + rh * 16 + ka] = a.x;
        At[(la + 1) * 512 + rh * 16 + ka] = a.y;
        At[(la + 2) * 512 + rh * 16 + ka] = a.z;
        At[(la + 3) * 512 + rh * 16 + ka] = a.w;
        float4 m = *(const float4*)(rel_msg + g0);
        int cm = g0 & 15, im = (g0 >> 4) & 15, hm = (g0 >> 8) & 7, rm = g0 >> 11;
        *(float4*)&Ml[rm * 2080 + hm * 260 + im * 16 + cm] = m;
    }
    __syncthreads();   // the ONLY barrier; everything below is wave-independent

    int w = tid >> 6;
    int lane = tid & 63;
    float* qA = scr[w];
    float* pl = scr[w] + 512;

    int hE = lane >> 4;               // head slice 0..3 (even-u), +4 for odd-u
    int j  = lane >> 3, h = lane & 7; // score mapping: lane = j*8 + h
    int h2 = lane >> 3, d0 = lane * 2;// aggr mapping: head h2, dims d0,d0+1
    int cp = (lane & 7) * 2;          // epilogue col pair within head

    for (int g = 0; g < 8; ++g) {
        int n = blockIdx.x * 32 + w * 8 + g;   // grid = NN/32 exactly
        int e_beg = row_start[n], e_end = row_start[n + 1];
        int tt = node_type[n];

        // q slices into registers (L1-served broadcast reads)
        const float4* qp  = (const float4*)(Qn + (size_t)n * 128 + hE * 16);
        const float4* qp2 = (const float4*)(Qn + (size_t)n * 128 + 64 + hE * 16);
        float4 qE0 = qp[0],  qE1 = qp[1],  qE2 = qp[2],  qE3 = qp[3];
        float4 qO0 = qp2[0], qO1 = qp2[1], qO2 = qp2[2], qO3 = qp2[3];

        // prefetch first meta chunk (32 edges) while prologue runs
        int4 mm = make_int4(0, 0, 0, 0);
        if (lane < 32 && e_beg + lane < e_end) mm = meta[e_beg + lane];

        // ---- prologue: qA[f]=sum_l q[h(f),l]*A[r,h,k,l] via At[l*512+f] ----
        #pragma unroll
        for (int u = 0; u < 8; ++u) {
            int f = u * 64 + lane;    // f = (r*8+h)*16 + k; h = (u*4+hE)&7
            const float* a = &At[f];
            float4 qa0 = (u & 1) ? qO0 : qE0;
            float4 qa1 = (u & 1) ? qO1 : qE1;
            float4 qa2 = (u & 1) ? qO2 : qE2;
            float4 qa3 = (u & 1) ? qO3 : qE3;
            float val = a[0*512]*qa0.x + a[1*512]*qa0.y + a[2*512]*qa0.z + a[3*512]*qa0.w
                      + a[4*512]*qa1.x + a[5*512]*qa1.y + a[6*512]*qa1.z + a[7*512]*qa1.w
                      + a[8*512]*qa2.x + a[9*512]*qa2.y + a[10*512]*qa2.z + a[11*512]*qa2.w
                      + a[12*512]*qa3.x + a[13*512]*qa3.y + a[14*512]*qa3.z + a[15*512]*qa3.w;
            qA[f] = val;
        }

        float ls = 0.f;
        float2 a0v = {0.f,0.f}, a1v = {0.f,0.f}, a2v = {0.f,0.f}, a3v = {0.f,0.f};
        int rmask = 0;

        for (int cb = e_beg; cb < e_end; cb += 32) {
            if (cb > e_beg) {
                mm = make_int4(0, 0, 0, 0);
                if (lane < 32 && cb + lane < e_end) mm = meta[cb + lane];
            }
            int cdeg = min(32, e_end - cb);
            // ---- score: 8 edges x 8 heads per pass; p -> wave-private LDS ----
            int nss = (cdeg + 7) >> 3;
            for (int ss = 0; ss < nss; ++ss) {
                int sl = ss * 8 + j;
                int ei = cb + sl;
                bool valid = ei < e_end;
                int mxs = __shfl(mm.x, sl, 64);
                int mys = __shfl(mm.y, sl, 64);
                int r = mys & 3, st = (mys >> 2) & 3, tb = mys >> 6;
                const float4* kp = (const float4*)(KV + (size_t)mxs * 256 + h * 16);
                const float4* tp = (const float4*)(ktv + (size_t)tb * 256 + h * 16);
                float4 k0 = kp[0], k1 = kp[1], k2 = kp[2], k3 = kp[3];
                float4 t0 = tp[0], t1 = tp[1], t2 = tp[2], t3 = tp[3];
                const float* qa = qA + r * 128 + h * 16;
                float s = (k0.x + t0.x) * qa[0]  + (k0.y + t0.y) * qa[1]
                        + (k0.z + t0.z) * qa[2]  + (k0.w + t0.w) * qa[3]
                        + (k1.x + t1.x) * qa[4]  + (k1.y + t1.y) * qa[5]
                        + (k1.z + t1.z) * qa[6]  + (k1.w + t1.w) * qa[7]
                        + (k2.x + t2.x) * qa[8]  + (k2.y + t2.y) * qa[9]
                        + (k2.z + t2.z) * qa[10] + (k2.w + t2.w) * qa[11]
                        + (k3.x + t3.x) * qa[12] + (k3.y + t3.y) * qa[13]
                        + (k3.z + t3.z) * qa[14] + (k3.w + t3.w) * qa[15];
                float pri = rel_pri[((tt * 4 + r) * 3 + st) * 8 + h];
                float p = valid ? __expf(s * pri * 0.25f) : 0.f;
                pl[ss * 64 + lane] = p;   // pl[sl*8 + h]: contiguous, conflict-free
                ls += p;
            }
            // ---- aggregation: serial over chunk edges, v gathered coalesced ----
            int mx = mm.x, my = mm.y;
            #pragma unroll 4
            for (int i = 0; i < cdeg; ++i) {
                int src  = __shfl(mx, i, 64);
                int code = __shfl(my, i, 64);
                int r = code & 3;
                float pv = pl[i * 8 + h2];   // broadcast within 8-lane groups
                float2 v1 = *(const float2*)(KV + (size_t)src * 256 + 128 + d0);
                float2 v2 = *(const float2*)(ktv + (size_t)(code >> 6) * 256 + 128 + d0);
                float vx = pv * (v1.x + v2.x);
                float vy = pv * (v1.y + v2.y);
                rmask |= (1 << r);
                switch (r) {
                    case 0: a0v.x += vx; a0v.y += vy; break;
                    case 1: a1v.x += vx; a1v.y += vy; break;
                    case 2: a2v.x += vx; a2v.y += vy; break;
                    default: a3v.x += vx; a3v.y += vy; break;
                }
            }
        }

        // ---- softmax denominator ----
        ls += __shfl_xor(ls, 8, 64);
        ls += __shfl_xor(ls, 16, 64);
        ls += __shfl_xor(ls, 32, 64);
        float lst = __shfl(ls, h2, 64);           // lane h2 holds total for head h2
        float iv = (lst > 0.f) ? (1.f / lst) : 0.f;

        // ---- epilogue: shfl-redistribute acc, rel_msg from LDS, gelu ----
        // acc[r][h2][2m]/[2m+1] live in lane h2*8+m as a_rv.x/.y
        float o0 = 0.f, o1 = 0.f;
        const float* Mb = &Ml[h2 * 260 + cp];
        #pragma unroll
        for (int r = 0; r < 4; ++r) {
            if (rmask & (1 << r)) {
                float sx, sy;
                #pragma unroll
                for (int m = 0; m < 8; ++m) {
                    if (r == 0)      { sx = __shfl(a0v.x, h2 * 8 + m, 64); sy = __shfl(a0v.y, h2 * 8 + m, 64); }
                    else if (r == 1) { sx = __shfl(a1v.x, h2 * 8 + m, 64); sy = __shfl(a1v.y, h2 * 8 + m, 64); }
                    else if (r == 2) { sx = __shfl(a2v.x, h2 * 8 + m, 64); sy = __shfl(a2v.y, h2 * 8 + m, 64); }
                    else             { sx = __shfl(a3v.x, h2 * 8 + m, 64); sy = __shfl(a3v.y, h2 * 8 + m, 64); }
                    float2 m0 = *(const float2*)&Mb[r * 2080 + (2 * m) * 16];
                    float2 m1 = *(const float2*)&Mb[r * 2080 + (2 * m + 1) * 16];
                    o0 += sx * m0.x + sy * m1.x;
                    o1 += sx * m0.y + sy * m1.y;
                }
            }
        }
        o0 *= iv; o1 *= iv;
        // exact gelu
        o0 = 0.5f * o0 * (1.f + erff(o0 * 0.7071067811865475f));
        o1 = 0.5f * o1 * (1.f + erff(o1 * 0.7071067811865475f));
        *(float2*)(h_out + (size_t)n * 128 + d0) = make_float2(o0, o1);
    }
}

// ---------------- launcher ----------------
extern "C" void kernel_launch(void* const* d_in, const int* in_sizes, int n_in,
                              void* d_out, int out_size, void* d_ws, size_t ws_size,
                              hipStream_t stream) {
    const float* node_feature = (const float*)d_in[0];
    const int*   node_type    = (const int*)d_in[1];
    const int*   edge_index   = (const int*)d_in[2];   // [2,E]: src then tgt
    const int*   edge_type    = (const int*)d_in[3];
    const int*   edge_time    = (const int*)d_in[4];
    const float* adapt_w      = (const float*)d_in[5];
    const float* adapt_b      = (const float*)d_in[6];
    const float* Wk           = (const float*)d_in[7];
    const float* bk           = (const float*)d_in[8];
    const float* Wq           = (const float*)d_in[9];
    const float* bq           = (const float*)d_in[10];
    const float* Wv           = (const float*)d_in[11];
    const float* bv           = (const float*)d_in[12];
    const float* Wa           = (const float*)d_in[13];
    const float* ba           = (const float*)d_in[14];
    const float* rel_pri      = (const float*)d_in[15];
    const float* rel_att      = (const float*)d_in[16];
    const float* rel_msg      = (const float*)d_in[17];
    const float* skip         = (const float*)d_in[18];
    const float* rte_w        = (const float*)d_in[19];
    const float* rte_b        = (const float*)d_in[20];
    float* out = (float*)d_out;

    const size_t ND = (size_t)NN * 128;
    float* Qn     = (float*)d_ws;            // N*128 (reused as h buffer)
    float* KV     = Qn + ND;                 // N*256 (k|v per row)
    float* rtab   = KV + 2 * ND;             // 240*256
    float* rproj  = rtab + 240 * 256;        // 240*128
    float* ktv    = rproj + 240 * 128;       // 720*256 (k|v per row)
    int*   cnt    = (int*)(ktv + 720 * 256);
    int*   fill   = cnt + NN;
    int*   row_st = fill + NN;               // NN+1 (+pad)
    int*   order  = row_st + NN + 4;         // NN
    int*   tcnt   = order + NN;              // 3 (+pad)
    int*   fill3  = tcnt + 4;                // 3 (+pad)
    int4*  meta   = (int4*)(fill3 + 4);      // EE int4
    // total ~165 MB

    const int* esrc = edge_index;
    const int* etgt = edge_index + EE;

    hipMemsetAsync(cnt, 0, 2 * NN * sizeof(int), stream);
    hipMemsetAsync(tcnt, 0, 8 * sizeof(int), stream);
    rte_tab_kernel<<<240, 256, 0, stream>>>(rtab);
    hist_kernel<<<(EE + 255) / 256, 256, 0, stream>>>(etgt, cnt);
    scan_kernel<<<1, 1024, 0, stream>>>(cnt, row_st);
    scatter_meta_kernel<<<(EE + 255) / 256, 256, 0, stream>>>(esrc, etgt, edge_type,
                                                              edge_time, node_type,
                                                              row_st, fill, meta);
    node_hist_kernel<<<(NN + 255) / 256, 256, 0, stream>>>(node_type, tcnt);
    node_scatter_kernel<<<(NN + 255) / 256, 256, 0, stream>>>(node_type, tcnt, fill3, order);

    // input adaptation: x = tanh(typed_linear(node_feature))
    typed_lin_kernel<0><<<NN / 32, 256, 0, stream>>>(node_feature, node_type, order,
                                                     adapt_w, adapt_b, nullptr, out);

    for (int l = 0; l < 2; ++l) {
        const float* Wk_l = Wk + l * 49152;  const float* bk_l = bk + l * 384;
        const float* Wq_l = Wq + l * 49152;  const float* bq_l = bq + l * 384;
        const float* Wv_l = Wv + l * 49152;  const float* bv_l = bv + l * 384;
        const float* Wa_l = Wa + l * 49152;  const float* ba_l = ba + l * 384;
        const float* pri_l = rel_pri + l * 288;
        const float* att_l = rel_att + l * 8192;
        const float* msg_l = rel_msg + l * 8192;
        const float* skip_l = skip + l * 3;
        const float* rte_w_l = rte_w + l * 32768;
        const float* rte_b_l = rte_b + l * 128;

        rte_proj_kernel<<<240, 128, 0, stream>>>(rtab, rte_w_l, rte_b_l, rproj);
        ktv_kernel<<<720, 128, 0, stream>>>(rproj, Wk_l, Wv_l, ktv);
        qkv_kernel<<<NN / 32, 256, 0, stream>>>(out, node_type, order, Wq_l, bq_l,
                                                Wk_l, bk_l, Wv_l, bv_l, Qn, KV);
        edge_kernel<<<NN / 32, 256, 0, stream>>>(Qn, KV, ktv, meta, node_type,
                                                 pri_l, att_l, msg_l, row_st,
                                                 Qn /* h overwrites own Qn rows: safe */);
        typed_lin_kernel<1><<<NN / 32, 256, 0, stream>>>(Qn, node_type, order, Wa_l, ba_l,
                                                         skip_l, out);
    }
}